// Round 10
// baseline (449.684 us; speedup 1.0000x reference)
//
#include <hip/hip_runtime.h>
#include <hip/hip_bf16.h>
#include <stdint.h>

#define D 1024
#define TEMP_INV (1.0f / 0.92f)
#define LOG2E 1.44269504f
#define EPS 1e-6f

typedef float f32x4_t __attribute__((ext_vector_type(4)));
typedef int   i32x4_t __attribute__((ext_vector_type(4)));
typedef int   i32x8_t __attribute__((ext_vector_type(8)));

typedef __attribute__((address_space(3))) void as3_void;
typedef const __attribute__((address_space(1))) void as1_void_c;

__device__ __forceinline__ void async_copy16(const uint8_t* g, uint8_t* l) {
    __builtin_amdgcn_global_load_lds((as1_void_c*)g, (as3_void*)l, 16, 0, 0);
}

// fp4 e2m1 nearest-value quantize -> 4-bit code {sign<<3 | mag}.
__device__ __forceinline__ uint32_t fp4_of(float x) {
    float a = __builtin_fabsf(x);
    uint32_t c;
    c = (a >= 0.25f) ? 1u : 0u;
    c = (a >= 0.75f) ? 2u : c;
    c = (a >= 1.25f) ? 3u : c;
    c = (a >= 1.75f) ? 4u : c;
    c = (a >= 2.5f)  ? 5u : c;
    c = (a >= 3.5f)  ? 6u : c;
    c = (a >= 5.0f)  ? 7u : c;
    return c | ((__float_as_uint(x) >> 28) & 8u);   // sign -> bit 3
}

__device__ __forceinline__ uint32_t pack8_fp4(float4 a0, float4 a1) {
    return  fp4_of(a0.x)        | (fp4_of(a0.y) << 4)  |
           (fp4_of(a0.z) << 8)  | (fp4_of(a0.w) << 12) |
           (fp4_of(a1.x) << 16) | (fp4_of(a1.y) << 20) |
           (fp4_of(a1.z) << 24) | (fp4_of(a1.w) << 28);
}

// undef-extend i32x4 fragment to the builtin's i32x8 operand (fp4 reads v[0:3])
__device__ __forceinline__ i32x8_t widen(i32x4_t v) {
    return __builtin_shufflevector(v, v, 0, 1, 2, 3, -1, -1, -1, -1);
}

// ---------------------------------------------------------------------------
// Kernel 1: verified (r5-r9). fp4 convert + exact fp32 norms + s1 + rowsum
// zero. Added: zero the gemm completion counter (block 0).
// ---------------------------------------------------------------------------
__global__ __launch_bounds__(256) void prep_kernel(
    const float* __restrict__ q, const float* __restrict__ p,
    const float* __restrict__ neg,
    uint8_t* __restrict__ Qb, uint8_t* __restrict__ Nb,
    float* __restrict__ iq, float* __restrict__ inx,
    float* __restrict__ s1, float* __restrict__ rowsum,
    unsigned* __restrict__ counter, int B)
{
    if (blockIdx.x == 0 && threadIdx.x == 0) *counter = 0;

    const int lane = threadIdx.x & 63;
    const int wid  = threadIdx.x >> 6;
    const int row  = blockIdx.x * 4 + wid;

    if (row < B) {
        const float4* qr = (const float4*)(q + (size_t)row * D);
        const float4* pr = (const float4*)(p + (size_t)row * D);
        uint32_t* qo = (uint32_t*)(Qb + (size_t)row * (D / 2));
        float qq = 0.f, pp = 0.f, qp = 0.f;
        #pragma unroll
        for (int pass = 0; pass < 2; ++pass) {
            const int f4 = pass * 128 + lane * 2;
            const float4 a0 = qr[f4], a1 = qr[f4 + 1];
            const float4 b0 = pr[f4], b1 = pr[f4 + 1];
            qq += a0.x*a0.x + a0.y*a0.y + a0.z*a0.z + a0.w*a0.w
                + a1.x*a1.x + a1.y*a1.y + a1.z*a1.z + a1.w*a1.w;
            pp += b0.x*b0.x + b0.y*b0.y + b0.z*b0.z + b0.w*b0.w
                + b1.x*b1.x + b1.y*b1.y + b1.z*b1.z + b1.w*b1.w;
            qp += a0.x*b0.x + a0.y*b0.y + a0.z*b0.z + a0.w*b0.w
                + a1.x*b1.x + a1.y*b1.y + a1.z*b1.z + a1.w*b1.w;
            qo[pass * 64 + lane] = pack8_fp4(a0, a1);
        }
        #pragma unroll
        for (int off = 32; off > 0; off >>= 1) {
            qq += __shfl_down(qq, off, 64);
            pp += __shfl_down(pp, off, 64);
            qp += __shfl_down(qp, off, 64);
        }
        if (lane == 0) {
            float qnv = sqrtf(qq);
            iq[row] = (TEMP_INV * LOG2E) / fmaxf(qnv, 1e-20f);
            float den = fmaxf(qnv * sqrtf(pp), EPS);
            s1[row] = expf((qp / den) * TEMP_INV);   // exact reference path
            rowsum[row] = 0.0f;
        }
    } else {
        const int r2 = row - B;
        const float4* nr = (const float4*)(neg + (size_t)r2 * D);
        uint32_t* no = (uint32_t*)(Nb + (size_t)r2 * (D / 2));
        float ss = 0.f;
        #pragma unroll
        for (int pass = 0; pass < 2; ++pass) {
            const int f4 = pass * 128 + lane * 2;
            const float4 n0 = nr[f4], n1 = nr[f4 + 1];
            ss += n0.x*n0.x + n0.y*n0.y + n0.z*n0.z + n0.w*n0.w
                + n1.x*n1.x + n1.y*n1.y + n1.z*n1.z + n1.w*n1.w;
            no[pass * 64 + lane] = pack8_fp4(n0, n1);
        }
        #pragma unroll
        for (int off = 32; off > 0; off >>= 1) ss += __shfl_down(ss, off, 64);
        if (lane == 0) inx[r2] = 1.0f / fmaxf(sqrtf(ss), 1e-20f);
    }
}

// ---------------------------------------------------------------------------
// Kernel 2 (round 10): 128x256 tile, 8 waves (2M x 4N), per-wave geometry
// IDENTICAL to the verified r7 kernel (4x4 acc = 64 f32, same identity-sigma
// 0-conflict maps, same stage->drain->compute cadence, 4 K-tiles of K=256).
// Scaling: 2x FLOPs per block at the SAME 4 drains -> drain cost per FLOP
// halved. LDS 48 KB (A 16 + B 32) -> 3 blocks/CU; staging 6 copies/thread
// (was 8). VGPR need ~90 < the 128-reg cap for 512-thread blocks (r1-r3
// spilled only because 256^2 needed 160+). Grid 2048 = 8 super-tiles of 256
// = one per XCD (A+B working set 3 MB < 4 MB XCD-L2).
// Finalize fused into the last block (threadfence + counter; rowsum read
// back via atomicAdd(+0) for cross-XCD coherence) -> one fewer launch.
// [ledger: r4 dbuf, r6 full-K, r9 two-tile all lost to this cadence; r8
//  no-LDS gathers lost 2x. Schedule surgery closed; this is shape scaling.]
// ---------------------------------------------------------------------------
__global__ __launch_bounds__(512) void gemm_exp_rowsum(
    const uint8_t* __restrict__ Qb, const uint8_t* __restrict__ Nb,
    const float* __restrict__ iq, const float* __restrict__ inx,
    float* __restrict__ rowsum, const float* __restrict__ s1,
    float* __restrict__ out, unsigned* __restrict__ counter,
    int nbx, int nby, int Bc, float invN)
{
    __shared__ __align__(16) uint8_t As[128 * 128];   // 16 KB (one K-tile)
    __shared__ __align__(16) uint8_t Bs[256 * 128];   // 32 KB
    __shared__ float red[8];
    __shared__ unsigned islast;

    // --- raster: bijective XCD chunking over 16x16 super-tiles ---
    const int nwg  = nbx * nby;                // 32 x 64 = 2048
    const int qx   = nwg >> 3;                 // 256 = one super-tile per XCD
    const int bid  = blockIdx.x;
    const int s    = (bid & 7) * qx + (bid >> 3);
    const int st   = s >> 8;
    const int w    = s & 255;
    const int nstx = nbx >> 4;                 // 2
    const int sty  = st / nstx, stx = st - sty * nstx;
    const int by   = sty * 16 + (w >> 4);
    const int bx   = stx * 16 + (w & 15);

    const int tid = threadIdx.x;               // 0..511
    const int i0 = by * 128;                   // Q rows
    const int j0 = bx * 256;                   // Neg rows

    const int lane = tid & 63;
    const int wid  = tid >> 6;                 // 0..7
    const int wm   = wid & 1;                  // A half
    const int wn   = wid >> 1;                 // B quarter 0..3
    const int quad = lane >> 4;
    const int lc   = lane & 15;
    const int xsw  = lc & 7;

    const int DB = D / 2;                      // 512 B per fp4 row

    // staging map (identity sigma, verified 0-conflict): thread t ->
    // row r_in = t>>3 (64-row rounds), slot = t&7, chunk = slot ^ (r_in&7).
    const int r_in = tid >> 3;                 // 0..63
    const int slot = tid & 7;
    const int csw  = slot ^ (r_in & 7);
    const uint8_t* gA0 = Qb + (size_t)(i0 + r_in) * DB + csw * 16;
    const uint8_t* gB0 = Nb + (size_t)(j0 + r_in) * DB + csw * 16;

    // read maps (verified 0-conflict): chunk quad -> slot quad^xsw (slo),
    // chunk quad+4 -> ^4 (byte ^64)
    const int slo = (quad ^ xsw) * 16;
    const int shi = slo ^ 64;

    f32x4_t acc[4][4];
    #pragma unroll
    for (int mi = 0; mi < 4; ++mi)
        #pragma unroll
        for (int ni = 0; ni < 4; ++ni)
            acc[mi][ni] = (f32x4_t){0.f, 0.f, 0.f, 0.f};

    for (int kt = 0; kt < DB; kt += 128) {   // 4 K-tiles (K=256 each)
        __syncthreads();   // protect LDS while other waves still reading
        #pragma unroll
        for (int c = 0; c < 2; ++c)          // A: 128 rows, 2 x 64-row rounds
            async_copy16(gA0 + kt + (size_t)c * (64 * DB),
                         As + tid * 16 + c * 8192);
        #pragma unroll
        for (int c = 0; c < 4; ++c)          // B: 256 rows, 4 rounds
            async_copy16(gB0 + kt + (size_t)c * (64 * DB),
                         Bs + tid * 16 + c * 8192);
        __syncthreads();   // drains vmcnt(0) before s_barrier

        const uint8_t* Abase = As + (size_t)(wm * 64 + lc) * 128;
        const uint8_t* Bbase = Bs + (size_t)(wn * 64 + lc) * 128;
        i32x4_t blo[4], bhi[4];
        #pragma unroll
        for (int ni = 0; ni < 4; ++ni) {
            blo[ni] = *(const i32x4_t*)(Bbase + ni * 2048 + slo);
            bhi[ni] = *(const i32x4_t*)(Bbase + ni * 2048 + shi);
        }
        #pragma unroll
        for (int mi = 0; mi < 4; ++mi) {
            const i32x8_t A0 = widen(*(const i32x4_t*)(Abase + mi * 2048 + slo));
            const i32x8_t A1 = widen(*(const i32x4_t*)(Abase + mi * 2048 + shi));
            #pragma unroll
            for (int ni = 0; ni < 4; ++ni) {
                acc[mi][ni] = __builtin_amdgcn_mfma_scale_f32_16x16x128_f8f6f4(
                    A0, widen(blo[ni]), acc[mi][ni],
                    4 /*A=fp4 e2m1*/, 4 /*B=fp4 e2m1*/,
                    0, 127 /*scale A = 2^0*/, 0, 127 /*scale B = 2^0*/);
                acc[mi][ni] = __builtin_amdgcn_mfma_scale_f32_16x16x128_f8f6f4(
                    A1, widen(bhi[ni]), acc[mi][ni],
                    4, 4, 0, 127, 0, 127);
            }
        }
    }

    // Epilogue (verified C/D layout: col = lane&15, row = quad*4 + reg).
    float inl[4];
    #pragma unroll
    for (int ni = 0; ni < 4; ++ni)
        inl[ni] = inx[j0 + wn * 64 + ni * 16 + lc];

    #pragma unroll
    for (int mi = 0; mi < 4; ++mi) {
        const int rbase = i0 + wm * 64 + mi * 16 + quad * 4;
        const float4 qv = *(const float4*)&iq[rbase];   // iq includes T^-1*log2e
        float qa[4] = {qv.x, qv.y, qv.z, qv.w};
        float rs[4] = {0.f, 0.f, 0.f, 0.f};
        #pragma unroll
        for (int ni = 0; ni < 4; ++ni) {
            #pragma unroll
            for (int r = 0; r < 4; ++r)
                rs[r] += __builtin_amdgcn_exp2f(acc[mi][ni][r] * qa[r] * inl[ni]);
        }
        #pragma unroll
        for (int m = 1; m < 16; m <<= 1) {
            #pragma unroll
            for (int r = 0; r < 4; ++r) rs[r] += __shfl_xor(rs[r], m, 64);
        }
        if (lc == 0) {
            #pragma unroll
            for (int r = 0; r < 4; ++r) atomicAdd(&rowsum[rbase + r], rs[r]);
        }
    }

    // --- fused finalize: last block computes the loss ---
    __threadfence();                 // make this thread's atomics visible
    __syncthreads();                 // all threads of block fenced
    if (tid == 0)
        islast = (atomicAdd(counter, 1u) == (unsigned)(nwg - 1));
    __syncthreads();
    if (islast) {
        float accv = 0.f;
        for (int i = tid; i < Bc; i += 512) {
            float rv = atomicAdd(&rowsum[i], 0.0f);   // coherent cross-XCD read
            float a  = s1[i];
            accv += __logf(a + rv * invN) - __logf(a);
        }
        #pragma unroll
        for (int off = 32; off > 0; off >>= 1) accv += __shfl_down(accv, off, 64);
        if (lane == 0) red[wid] = accv;
        __syncthreads();
        if (tid == 0) {
            float t = 0.f;
            #pragma unroll
            for (int k = 0; k < 8; ++k) t += red[k];
            out[0] = t / (float)Bc;
        }
    }
}

extern "C" void kernel_launch(void* const* d_in, const int* in_sizes, int n_in,
                              void* d_out, int out_size, void* d_ws, size_t ws_size,
                              hipStream_t stream) {
    const float* q   = (const float*)d_in[0];
    const float* p   = (const float*)d_in[1];
    const float* neg = (const float*)d_in[2];
    const int B = in_sizes[0] / D;
    const int N = in_sizes[2] / D;

    char* ws = (char*)d_ws;
    uint8_t*  Qb      = (uint8_t*)ws;                              // B * D/2
    uint8_t*  Nb      = (uint8_t*)(ws + (size_t)B * (D / 2));      // N * D/2
    float*    iq      = (float*)(ws + (size_t)(B + N) * (D / 2));
    float*    inx     = iq + B;
    float*    s1      = inx + N;
    float*    rowsum  = s1 + B;
    unsigned* counter = (unsigned*)(rowsum + B);

    const int nbx = N / 256, nby = B / 128;   // 32 x 64 = 2048 blocks
    prep_kernel<<<(B + N) / 4, 256, 0, stream>>>(q, p, neg, Qb, Nb, iq, inx,
                                                 s1, rowsum, counter, B);
    gemm_exp_rowsum<<<nbx * nby, 512, 0, stream>>>(Qb, Nb, iq, inx, rowsum,
                                                   s1, (float*)d_out, counter,
                                                   nbx, nby, B, 1.0f / (float)N);
}

// Round 11
// 421.201 us; speedup vs baseline: 1.0676x; 1.0676x over previous
//
#include <hip/hip_runtime.h>
#include <hip/hip_bf16.h>
#include <stdint.h>

#define D 1024
#define TEMP_INV (1.0f / 0.92f)
#define LOG2E 1.44269504f
#define EPS 1e-6f

typedef float f32x4_t __attribute__((ext_vector_type(4)));
typedef int   i32x4_t __attribute__((ext_vector_type(4)));
typedef int   i32x8_t __attribute__((ext_vector_type(8)));

typedef __attribute__((address_space(3))) void as3_void;
typedef const __attribute__((address_space(1))) void as1_void_c;

__device__ __forceinline__ void async_copy16(const uint8_t* g, uint8_t* l) {
    __builtin_amdgcn_global_load_lds((as1_void_c*)g, (as3_void*)l, 16, 0, 0);
}

// fp4 e2m1 nearest-value quantize -> 4-bit code {sign<<3 | mag}.
__device__ __forceinline__ uint32_t fp4_of(float x) {
    float a = __builtin_fabsf(x);
    uint32_t c;
    c = (a >= 0.25f) ? 1u : 0u;
    c = (a >= 0.75f) ? 2u : c;
    c = (a >= 1.25f) ? 3u : c;
    c = (a >= 1.75f) ? 4u : c;
    c = (a >= 2.5f)  ? 5u : c;
    c = (a >= 3.5f)  ? 6u : c;
    c = (a >= 5.0f)  ? 7u : c;
    return c | ((__float_as_uint(x) >> 28) & 8u);   // sign -> bit 3
}

__device__ __forceinline__ uint32_t pack8_fp4(float4 a0, float4 a1) {
    return  fp4_of(a0.x)        | (fp4_of(a0.y) << 4)  |
           (fp4_of(a0.z) << 8)  | (fp4_of(a0.w) << 12) |
           (fp4_of(a1.x) << 16) | (fp4_of(a1.y) << 20) |
           (fp4_of(a1.z) << 24) | (fp4_of(a1.w) << 28);
}

// undef-extend i32x4 fragment to the builtin's i32x8 operand (fp4 reads v[0:3])
__device__ __forceinline__ i32x8_t widen(i32x4_t v) {
    return __builtin_shufflevector(v, v, 0, 1, 2, 3, -1, -1, -1, -1);
}

// ---------------------------------------------------------------------------
// Kernel 1: verified (r5-r10). fp4 convert + exact fp32 norms + s1 + rowsum
// zero. Block 0 also zeroes the gemm completion counter.
// ---------------------------------------------------------------------------
__global__ __launch_bounds__(256) void prep_kernel(
    const float* __restrict__ q, const float* __restrict__ p,
    const float* __restrict__ neg,
    uint8_t* __restrict__ Qb, uint8_t* __restrict__ Nb,
    float* __restrict__ iq, float* __restrict__ inx,
    float* __restrict__ s1, float* __restrict__ rowsum,
    unsigned* __restrict__ counter, int B)
{
    if (blockIdx.x == 0 && threadIdx.x == 0) *counter = 0;

    const int lane = threadIdx.x & 63;
    const int wid  = threadIdx.x >> 6;
    const int row  = blockIdx.x * 4 + wid;

    if (row < B) {
        const float4* qr = (const float4*)(q + (size_t)row * D);
        const float4* pr = (const float4*)(p + (size_t)row * D);
        uint32_t* qo = (uint32_t*)(Qb + (size_t)row * (D / 2));
        float qq = 0.f, pp = 0.f, qp = 0.f;
        #pragma unroll
        for (int pass = 0; pass < 2; ++pass) {
            const int f4 = pass * 128 + lane * 2;
            const float4 a0 = qr[f4], a1 = qr[f4 + 1];
            const float4 b0 = pr[f4], b1 = pr[f4 + 1];
            qq += a0.x*a0.x + a0.y*a0.y + a0.z*a0.z + a0.w*a0.w
                + a1.x*a1.x + a1.y*a1.y + a1.z*a1.z + a1.w*a1.w;
            pp += b0.x*b0.x + b0.y*b0.y + b0.z*b0.z + b0.w*b0.w
                + b1.x*b1.x + b1.y*b1.y + b1.z*b1.z + b1.w*b1.w;
            qp += a0.x*b0.x + a0.y*b0.y + a0.z*b0.z + a0.w*b0.w
                + a1.x*b1.x + a1.y*b1.y + a1.z*b1.z + a1.w*b1.w;
            qo[pass * 64 + lane] = pack8_fp4(a0, a1);
        }
        #pragma unroll
        for (int off = 32; off > 0; off >>= 1) {
            qq += __shfl_down(qq, off, 64);
            pp += __shfl_down(pp, off, 64);
            qp += __shfl_down(qp, off, 64);
        }
        if (lane == 0) {
            float qnv = sqrtf(qq);
            iq[row] = (TEMP_INV * LOG2E) / fmaxf(qnv, 1e-20f);
            float den = fmaxf(qnv * sqrtf(pp), EPS);
            s1[row] = expf((qp / den) * TEMP_INV);   // exact reference path
            rowsum[row] = 0.0f;
        }
    } else {
        const int r2 = row - B;
        const float4* nr = (const float4*)(neg + (size_t)r2 * D);
        uint32_t* no = (uint32_t*)(Nb + (size_t)r2 * (D / 2));
        float ss = 0.f;
        #pragma unroll
        for (int pass = 0; pass < 2; ++pass) {
            const int f4 = pass * 128 + lane * 2;
            const float4 n0 = nr[f4], n1 = nr[f4 + 1];
            ss += n0.x*n0.x + n0.y*n0.y + n0.z*n0.z + n0.w*n0.w
                + n1.x*n1.x + n1.y*n1.y + n1.z*n1.z + n1.w*n1.w;
            no[pass * 64 + lane] = pack8_fp4(n0, n1);
        }
        #pragma unroll
        for (int off = 32; off > 0; off >>= 1) ss += __shfl_down(ss, off, 64);
        if (lane == 0) inx[r2] = 1.0f / fmaxf(sqrtf(ss), 1e-20f);
    }
}

// ---------------------------------------------------------------------------
// Kernel 2 (round 11): EXACT r7 gemm (best verified: 72 us, 0 conflicts,
// 12.4 MB FETCH) + fused finalize tail (r10-validated mechanism) at 256 thr.
// [Session ledger -- locked conclusions:
//   * 256-thr stage->drain->compute cadence is the floor of the schedule
//     axis: dbuf r4, full-K r6, two-tile r9, counted-vmcnt r1-r3 all lost.
//   * 512-thr blocks are toolchain-poison: 320-370 us with AND without
//     spill (r1,r2,r3,r10) vs 72-152 us for every 256-thr variant.
//   * no-LDS direct-fragment gathers: 2x loss (r8).]
// ---------------------------------------------------------------------------
__global__ __launch_bounds__(256) void gemm_exp_rowsum(
    const uint8_t* __restrict__ Qb, const uint8_t* __restrict__ Nb,
    const float* __restrict__ iq, const float* __restrict__ inx,
    float* __restrict__ rowsum, const float* __restrict__ s1,
    float* __restrict__ out, unsigned* __restrict__ counter,
    int nbx, int nby, int Bc, float invN)
{
    __shared__ __align__(16) uint8_t As[128 * 128];   // 16 KB
    __shared__ __align__(16) uint8_t Bs[128 * 128];   // 16 KB
    __shared__ float red[4];
    __shared__ unsigned islast;

    // --- raster: bijective XCD chunking over 16x16 super-tiles (verified r7)
    const int nwg  = nbx * nby;
    const int qx   = nwg >> 3;                 // blocks per XCD (nwg % 8 == 0)
    const int bid  = blockIdx.x;
    const int s    = (bid & 7) * qx + (bid >> 3);
    const int st   = s >> 8;                   // super-tile id (256 blocks)
    const int w    = s & 255;
    const int nstx = nbx >> 4;
    const int sty  = st / nstx, stx = st - sty * nstx;
    const int by   = sty * 16 + (w >> 4);
    const int bx   = stx * 16 + (w & 15);

    const int tid = threadIdx.x;
    const int i0 = by * 128;   // Q rows
    const int j0 = bx * 128;   // Neg rows

    const int lane = tid & 63;
    const int wid  = tid >> 6;
    const int wm   = wid & 1;          // wave row (2x2 wave grid)
    const int wn   = wid >> 1;         // wave col
    const int quad = lane >> 4;
    const int lc   = lane & 15;
    const int xsw  = lc & 7;           // read-side XOR key

    const int DB = D / 2;              // 512 B per fp4 row

    // staging map (identity sigma, verified 0-conflict r6/r7): thread t ->
    // row r_in = t>>3 (per 32-row round), slot s = t&7; fetch chunk
    // c = s ^ (r_in&7); LDS dest = t*16 (linear).
    const int r_in = tid >> 3;
    const int slot = tid & 7;
    const int csw  = slot ^ (r_in & 7);
    const uint8_t* gA0 = Qb + (size_t)(i0 + r_in) * DB + csw * 16;
    const uint8_t* gB0 = Nb + (size_t)(j0 + r_in) * DB + csw * 16;
    uint8_t* la = As + tid * 16;
    uint8_t* lb = Bs + tid * 16;

    // LDS read bases: row = wm*64 + mi*16 + lc, 128 B/row.
    // chunk quad   (K 0..127)   -> slot quad^xsw   -> byte slo
    // chunk quad+4 (K 128..255) -> slot quad^xsw^4 -> byte slo^64
    const uint8_t* Abase = As + (size_t)(wm * 64 + lc) * 128;
    const uint8_t* Bbase = Bs + (size_t)(wn * 64 + lc) * 128;
    const int slo = (quad ^ xsw) * 16;
    const int shi = slo ^ 64;

    f32x4_t acc[4][4];
    #pragma unroll
    for (int mi = 0; mi < 4; ++mi)
        #pragma unroll
        for (int ni = 0; ni < 4; ++ni)
            acc[mi][ni] = (f32x4_t){0.f, 0.f, 0.f, 0.f};

    for (int kt = 0; kt < DB; kt += 128) {   // 4 iters (K=256 each)
        __syncthreads();   // protect LDS while other waves still reading
        #pragma unroll
        for (int c = 0; c < 4; ++c) {
            async_copy16(gA0 + kt + (size_t)c * (32 * DB), la + c * 4096);
            async_copy16(gB0 + kt + (size_t)c * (32 * DB), lb + c * 4096);
        }
        __syncthreads();   // drains vmcnt(0) before s_barrier

        i32x4_t blo[4], bhi[4];
        #pragma unroll
        for (int ni = 0; ni < 4; ++ni) {
            blo[ni] = *(const i32x4_t*)(Bbase + ni * 2048 + slo);
            bhi[ni] = *(const i32x4_t*)(Bbase + ni * 2048 + shi);
        }
        #pragma unroll
        for (int mi = 0; mi < 4; ++mi) {
            const i32x8_t A0 = widen(*(const i32x4_t*)(Abase + mi * 2048 + slo));
            const i32x8_t A1 = widen(*(const i32x4_t*)(Abase + mi * 2048 + shi));
            #pragma unroll
            for (int ni = 0; ni < 4; ++ni) {
                acc[mi][ni] = __builtin_amdgcn_mfma_scale_f32_16x16x128_f8f6f4(
                    A0, widen(blo[ni]), acc[mi][ni],
                    4 /*A=fp4 e2m1*/, 4 /*B=fp4 e2m1*/,
                    0, 127 /*scale A = 2^0*/, 0, 127 /*scale B = 2^0*/);
                acc[mi][ni] = __builtin_amdgcn_mfma_scale_f32_16x16x128_f8f6f4(
                    A1, widen(bhi[ni]), acc[mi][ni],
                    4, 4, 0, 127, 0, 127);
            }
        }
    }

    // Epilogue (verified C/D layout: col = lane&15, row = quad*4 + reg).
    float inl[4];
    #pragma unroll
    for (int ni = 0; ni < 4; ++ni)
        inl[ni] = inx[j0 + wn * 64 + ni * 16 + lc];

    #pragma unroll
    for (int mi = 0; mi < 4; ++mi) {
        const int rbase = i0 + wm * 64 + mi * 16 + quad * 4;
        const float4 qv = *(const float4*)&iq[rbase];   // iq includes T^-1*log2e
        float qa[4] = {qv.x, qv.y, qv.z, qv.w};
        float rs[4] = {0.f, 0.f, 0.f, 0.f};
        #pragma unroll
        for (int ni = 0; ni < 4; ++ni) {
            #pragma unroll
            for (int r = 0; r < 4; ++r)
                rs[r] += __builtin_amdgcn_exp2f(acc[mi][ni][r] * qa[r] * inl[ni]);
        }
        #pragma unroll
        for (int m = 1; m < 16; m <<= 1) {
            #pragma unroll
            for (int r = 0; r < 4; ++r) rs[r] += __shfl_xor(rs[r], m, 64);
        }
        if (lc == 0) {
            #pragma unroll
            for (int r = 0; r < 4; ++r) atomicAdd(&rowsum[rbase + r], rs[r]);
        }
    }

    // --- fused finalize (r10-validated mechanism): last block computes loss.
    __threadfence();                 // make this block's atomics visible
    __syncthreads();
    if (tid == 0)
        islast = (atomicAdd(counter, 1u) == (unsigned)(nwg - 1));
    __syncthreads();
    if (islast) {
        float accv = 0.f;
        for (int i = tid; i < Bc; i += 256) {
            float rv = atomicAdd(&rowsum[i], 0.0f);   // coherent cross-XCD read
            float a  = s1[i];
            accv += __logf(a + rv * invN) - __logf(a);
        }
        #pragma unroll
        for (int off = 32; off > 0; off >>= 1) accv += __shfl_down(accv, off, 64);
        if (lane == 0) red[wid] = accv;
        __syncthreads();
        if (tid == 0)
            out[0] = (red[0] + red[1] + red[2] + red[3]) / (float)Bc;
    }
}

extern "C" void kernel_launch(void* const* d_in, const int* in_sizes, int n_in,
                              void* d_out, int out_size, void* d_ws, size_t ws_size,
                              hipStream_t stream) {
    const float* q   = (const float*)d_in[0];
    const float* p   = (const float*)d_in[1];
    const float* neg = (const float*)d_in[2];
    const int B = in_sizes[0] / D;
    const int N = in_sizes[2] / D;

    char* ws = (char*)d_ws;
    uint8_t*  Qb      = (uint8_t*)ws;                              // B * D/2
    uint8_t*  Nb      = (uint8_t*)(ws + (size_t)B * (D / 2));      // N * D/2
    float*    iq      = (float*)(ws + (size_t)(B + N) * (D / 2));
    float*    inx     = iq + B;
    float*    s1      = inx + N;
    float*    rowsum  = s1 + B;
    unsigned* counter = (unsigned*)(rowsum + B);

    const int nbx = N / 128, nby = B / 128;   // 64 x 64 = 4096 blocks
    prep_kernel<<<(B + N) / 4, 256, 0, stream>>>(q, p, neg, Qb, Nb, iq, inx,
                                                 s1, rowsum, counter, B);
    gemm_exp_rowsum<<<nbx * nby, 256, 0, stream>>>(Qb, Nb, iq, inx, rowsum,
                                                   s1, (float*)d_out, counter,
                                                   nbx, nby, B, 1.0f / (float)N);
}

// Round 12
// 190.634 us; speedup vs baseline: 2.3589x; 2.2095x over previous
//
#include <hip/hip_runtime.h>
#include <hip/hip_bf16.h>
#include <stdint.h>

#define D 1024
#define TEMP_INV (1.0f / 0.92f)
#define LOG2E 1.44269504f
#define EPS 1e-6f

typedef float f32x4_t __attribute__((ext_vector_type(4)));
typedef int   i32x4_t __attribute__((ext_vector_type(4)));
typedef int   i32x8_t __attribute__((ext_vector_type(8)));

typedef __attribute__((address_space(3))) void as3_void;
typedef const __attribute__((address_space(1))) void as1_void_c;

__device__ __forceinline__ void async_copy16(const uint8_t* g, uint8_t* l) {
    __builtin_amdgcn_global_load_lds((as1_void_c*)g, (as3_void*)l, 16, 0, 0);
}

// fp4 e2m1 nearest-value quantize -> 4-bit code {sign<<3 | mag}.
__device__ __forceinline__ uint32_t fp4_of(float x) {
    float a = __builtin_fabsf(x);
    uint32_t c;
    c = (a >= 0.25f) ? 1u : 0u;
    c = (a >= 0.75f) ? 2u : c;
    c = (a >= 1.25f) ? 3u : c;
    c = (a >= 1.75f) ? 4u : c;
    c = (a >= 2.5f)  ? 5u : c;
    c = (a >= 3.5f)  ? 6u : c;
    c = (a >= 5.0f)  ? 7u : c;
    return c | ((__float_as_uint(x) >> 28) & 8u);   // sign -> bit 3
}

__device__ __forceinline__ uint32_t pack8_fp4(float4 a0, float4 a1) {
    return  fp4_of(a0.x)        | (fp4_of(a0.y) << 4)  |
           (fp4_of(a0.z) << 8)  | (fp4_of(a0.w) << 12) |
           (fp4_of(a1.x) << 16) | (fp4_of(a1.y) << 20) |
           (fp4_of(a1.z) << 24) | (fp4_of(a1.w) << 28);
}

// undef-extend i32x4 fragment to the builtin's i32x8 operand (fp4 reads v[0:3])
__device__ __forceinline__ i32x8_t widen(i32x4_t v) {
    return __builtin_shufflevector(v, v, 0, 1, 2, 3, -1, -1, -1, -1);
}

// ---------------------------------------------------------------------------
// Kernel 1: verified (r5-r7). fp4 convert + exact fp32 norms + s1 + rowsum 0.
// ---------------------------------------------------------------------------
__global__ __launch_bounds__(256) void prep_kernel(
    const float* __restrict__ q, const float* __restrict__ p,
    const float* __restrict__ neg,
    uint8_t* __restrict__ Qb, uint8_t* __restrict__ Nb,
    float* __restrict__ iq, float* __restrict__ inx,
    float* __restrict__ s1, float* __restrict__ rowsum, int B)
{
    const int lane = threadIdx.x & 63;
    const int wid  = threadIdx.x >> 6;
    const int row  = blockIdx.x * 4 + wid;

    if (row < B) {
        const float4* qr = (const float4*)(q + (size_t)row * D);
        const float4* pr = (const float4*)(p + (size_t)row * D);
        uint32_t* qo = (uint32_t*)(Qb + (size_t)row * (D / 2));
        float qq = 0.f, pp = 0.f, qp = 0.f;
        #pragma unroll
        for (int pass = 0; pass < 2; ++pass) {
            const int f4 = pass * 128 + lane * 2;
            const float4 a0 = qr[f4], a1 = qr[f4 + 1];
            const float4 b0 = pr[f4], b1 = pr[f4 + 1];
            qq += a0.x*a0.x + a0.y*a0.y + a0.z*a0.z + a0.w*a0.w
                + a1.x*a1.x + a1.y*a1.y + a1.z*a1.z + a1.w*a1.w;
            pp += b0.x*b0.x + b0.y*b0.y + b0.z*b0.z + b0.w*b0.w
                + b1.x*b1.x + b1.y*b1.y + b1.z*b1.z + b1.w*b1.w;
            qp += a0.x*b0.x + a0.y*b0.y + a0.z*b0.z + a0.w*b0.w
                + a1.x*b1.x + a1.y*b1.y + a1.z*b1.z + a1.w*b1.w;
            qo[pass * 64 + lane] = pack8_fp4(a0, a1);
        }
        #pragma unroll
        for (int off = 32; off > 0; off >>= 1) {
            qq += __shfl_down(qq, off, 64);
            pp += __shfl_down(pp, off, 64);
            qp += __shfl_down(qp, off, 64);
        }
        if (lane == 0) {
            float qnv = sqrtf(qq);
            iq[row] = (TEMP_INV * LOG2E) / fmaxf(qnv, 1e-20f);
            float den = fmaxf(qnv * sqrtf(pp), EPS);
            s1[row] = expf((qp / den) * TEMP_INV);   // exact reference path
            rowsum[row] = 0.0f;
        }
    } else {
        const int r2 = row - B;
        const float4* nr = (const float4*)(neg + (size_t)r2 * D);
        uint32_t* no = (uint32_t*)(Nb + (size_t)r2 * (D / 2));
        float ss = 0.f;
        #pragma unroll
        for (int pass = 0; pass < 2; ++pass) {
            const int f4 = pass * 128 + lane * 2;
            const float4 n0 = nr[f4], n1 = nr[f4 + 1];
            ss += n0.x*n0.x + n0.y*n0.y + n0.z*n0.z + n0.w*n0.w
                + n1.x*n1.x + n1.y*n1.y + n1.z*n1.z + n1.w*n1.w;
            no[pass * 64 + lane] = pack8_fp4(n0, n1);
        }
        #pragma unroll
        for (int off = 32; off > 0; off >>= 1) ss += __shfl_down(ss, off, 64);
        if (lane == 0) inx[r2] = 1.0f / fmaxf(sqrtf(ss), 1e-20f);
    }
}

// ---------------------------------------------------------------------------
// Kernel 2: EXACT r7 gemm (best verified: 72 us gemm, 191.5 us total,
// 0 bank conflicts, 12.4 MB FETCH).
// [Session ledger -- locked conclusions on this toolchain/op:
//   * 256-thr stage->drain->compute, 32 KB LDS = floor of the schedule axis
//     (dbuf r4 +9%, full-K r6 +100%, two-tile r9 +18%, counted-vmcnt r1-r3).
//   * no-LDS direct-fragment gathers: 2x loss (r8; 16 txns/load).
//   * 512-thr blocks: 320-370 us with and without spill (r1-r3, r10).
//   * per-block __threadfence() (fused finalize, r10/r11): L2 wb+inv per
//     block wipes XCD-L2 panel residency -> 4.4x loss. NEVER fence the
//     hot path on non-coherent-L2 hardware.]
// ---------------------------------------------------------------------------
__global__ __launch_bounds__(256) void gemm_exp_rowsum(
    const uint8_t* __restrict__ Qb, const uint8_t* __restrict__ Nb,
    const float* __restrict__ iq, const float* __restrict__ inx,
    float* __restrict__ rowsum, int nbx, int nby)
{
    __shared__ __align__(16) uint8_t As[128 * 128];   // 16 KB
    __shared__ __align__(16) uint8_t Bs[128 * 128];   // 16 KB

    // --- raster: bijective XCD chunking over 16x16 super-tiles (verified r7)
    const int nwg  = nbx * nby;
    const int qx   = nwg >> 3;                 // blocks per XCD (nwg % 8 == 0)
    const int bid  = blockIdx.x;
    const int s    = (bid & 7) * qx + (bid >> 3);
    const int st   = s >> 8;                   // super-tile id (256 blocks)
    const int w    = s & 255;
    const int nstx = nbx >> 4;
    const int sty  = st / nstx, stx = st - sty * nstx;
    const int by   = sty * 16 + (w >> 4);
    const int bx   = stx * 16 + (w & 15);

    const int tid = threadIdx.x;
    const int i0 = by * 128;   // Q rows
    const int j0 = bx * 128;   // Neg rows

    const int lane = tid & 63;
    const int wid  = tid >> 6;
    const int wm   = wid & 1;          // wave row (2x2 wave grid)
    const int wn   = wid >> 1;         // wave col
    const int quad = lane >> 4;
    const int lc   = lane & 15;
    const int xsw  = lc & 7;           // read-side XOR key

    const int DB = D / 2;              // 512 B per fp4 row

    // staging map (identity sigma, verified 0-conflict r6/r7): thread t ->
    // row r_in = t>>3 (per 32-row round), slot s = t&7; fetch chunk
    // c = s ^ (r_in&7); LDS dest = t*16 (linear).
    const int r_in = tid >> 3;
    const int slot = tid & 7;
    const int csw  = slot ^ (r_in & 7);
    const uint8_t* gA0 = Qb + (size_t)(i0 + r_in) * DB + csw * 16;
    const uint8_t* gB0 = Nb + (size_t)(j0 + r_in) * DB + csw * 16;
    uint8_t* la = As + tid * 16;
    uint8_t* lb = Bs + tid * 16;

    // LDS read bases: row = wm*64 + mi*16 + lc, 128 B/row.
    // chunk quad   (K 0..127)   -> slot quad^xsw   -> byte slo
    // chunk quad+4 (K 128..255) -> slot quad^xsw^4 -> byte slo^64
    const uint8_t* Abase = As + (size_t)(wm * 64 + lc) * 128;
    const uint8_t* Bbase = Bs + (size_t)(wn * 64 + lc) * 128;
    const int slo = (quad ^ xsw) * 16;
    const int shi = slo ^ 64;

    f32x4_t acc[4][4];
    #pragma unroll
    for (int mi = 0; mi < 4; ++mi)
        #pragma unroll
        for (int ni = 0; ni < 4; ++ni)
            acc[mi][ni] = (f32x4_t){0.f, 0.f, 0.f, 0.f};

    for (int kt = 0; kt < DB; kt += 128) {   // 4 iters (K=256 each)
        __syncthreads();   // protect LDS while other waves still reading
        #pragma unroll
        for (int c = 0; c < 4; ++c) {
            async_copy16(gA0 + kt + (size_t)c * (32 * DB), la + c * 4096);
            async_copy16(gB0 + kt + (size_t)c * (32 * DB), lb + c * 4096);
        }
        __syncthreads();   // drains vmcnt(0) before s_barrier

        i32x4_t blo[4], bhi[4];
        #pragma unroll
        for (int ni = 0; ni < 4; ++ni) {
            blo[ni] = *(const i32x4_t*)(Bbase + ni * 2048 + slo);
            bhi[ni] = *(const i32x4_t*)(Bbase + ni * 2048 + shi);
        }
        #pragma unroll
        for (int mi = 0; mi < 4; ++mi) {
            const i32x8_t A0 = widen(*(const i32x4_t*)(Abase + mi * 2048 + slo));
            const i32x8_t A1 = widen(*(const i32x4_t*)(Abase + mi * 2048 + shi));
            #pragma unroll
            for (int ni = 0; ni < 4; ++ni) {
                acc[mi][ni] = __builtin_amdgcn_mfma_scale_f32_16x16x128_f8f6f4(
                    A0, widen(blo[ni]), acc[mi][ni],
                    4 /*A=fp4 e2m1*/, 4 /*B=fp4 e2m1*/,
                    0, 127 /*scale A = 2^0*/, 0, 127 /*scale B = 2^0*/);
                acc[mi][ni] = __builtin_amdgcn_mfma_scale_f32_16x16x128_f8f6f4(
                    A1, widen(bhi[ni]), acc[mi][ni],
                    4, 4, 0, 127, 0, 127);
            }
        }
    }

    // Epilogue (verified C/D layout: col = lane&15, row = quad*4 + reg).
    float inl[4];
    #pragma unroll
    for (int ni = 0; ni < 4; ++ni)
        inl[ni] = inx[j0 + wn * 64 + ni * 16 + lc];

    #pragma unroll
    for (int mi = 0; mi < 4; ++mi) {
        const int rbase = i0 + wm * 64 + mi * 16 + quad * 4;
        const float4 qv = *(const float4*)&iq[rbase];   // iq includes T^-1*log2e
        float qa[4] = {qv.x, qv.y, qv.z, qv.w};
        float rs[4] = {0.f, 0.f, 0.f, 0.f};
        #pragma unroll
        for (int ni = 0; ni < 4; ++ni) {
            #pragma unroll
            for (int r = 0; r < 4; ++r)
                rs[r] += __builtin_amdgcn_exp2f(acc[mi][ni][r] * qa[r] * inl[ni]);
        }
        #pragma unroll
        for (int m = 1; m < 16; m <<= 1) {
            #pragma unroll
            for (int r = 0; r < 4; ++r) rs[r] += __shfl_xor(rs[r], m, 64);
        }
        if (lc == 0) {
            #pragma unroll
            for (int r = 0; r < 4; ++r) atomicAdd(&rowsum[rbase + r], rs[r]);
        }
    }
}

// ---------------------------------------------------------------------------
// Kernel 3: unchanged (verified). loss = mean_b( log(s1+s2) - log(s1) ).
// ---------------------------------------------------------------------------
__global__ __launch_bounds__(256) void finalize_kernel(
    const float* __restrict__ s1, const float* __restrict__ rowsum,
    float* __restrict__ out, int B, float invN)
{
    __shared__ float red[4];
    const float4* s4 = (const float4*)s1;
    const float4* r4 = (const float4*)rowsum;
    float acc = 0.f;
    for (int i = threadIdx.x; i < B / 4; i += 256) {
        float4 a = s4[i];
        float4 s = r4[i];
        acc += __logf(a.x + s.x * invN) - __logf(a.x);
        acc += __logf(a.y + s.y * invN) - __logf(a.y);
        acc += __logf(a.z + s.z * invN) - __logf(a.z);
        acc += __logf(a.w + s.w * invN) - __logf(a.w);
    }
    #pragma unroll
    for (int off = 32; off > 0; off >>= 1) acc += __shfl_down(acc, off, 64);
    if ((threadIdx.x & 63) == 0) red[threadIdx.x >> 6] = acc;
    __syncthreads();
    if (threadIdx.x == 0)
        out[0] = (red[0] + red[1] + red[2] + red[3]) / (float)B;
}

extern "C" void kernel_launch(void* const* d_in, const int* in_sizes, int n_in,
                              void* d_out, int out_size, void* d_ws, size_t ws_size,
                              hipStream_t stream) {
    const float* q   = (const float*)d_in[0];
    const float* p   = (const float*)d_in[1];
    const float* neg = (const float*)d_in[2];
    const int B = in_sizes[0] / D;
    const int N = in_sizes[2] / D;

    char* ws = (char*)d_ws;
    uint8_t* Qb     = (uint8_t*)ws;                              // B * D/2
    uint8_t* Nb     = (uint8_t*)(ws + (size_t)B * (D / 2));      // N * D/2
    float*   iq     = (float*)(ws + (size_t)(B + N) * (D / 2));
    float*   inx    = iq + B;
    float*   s1     = inx + N;
    float*   rowsum = s1 + B;

    const int nbx = N / 128, nby = B / 128;   // 64 x 64 = 4096 blocks
    prep_kernel<<<(B + N) / 4, 256, 0, stream>>>(q, p, neg, Qb, Nb, iq, inx, s1, rowsum, B);
    gemm_exp_rowsum<<<nbx * nby, 256, 0, stream>>>(Qb, Nb, iq, inx, rowsum, nbx, nby);
    finalize_kernel<<<1, 256, 0, stream>>>(s1, rowsum, (float*)d_out, B, 1.0f / (float)N);
}